// Round 1
// baseline (178.903 us; speedup 1.0000x reference)
//
#include <hip/hip_runtime.h>
#include <math.h>

#define AN 120000
#define BN 16
#define GN 32
#define NBX ((AN + 255) / 256)   // 469 blocks along anchors

__device__ __forceinline__ float sl1(float d) {
    float ad = fabsf(d);
    return ad < 1.0f ? 0.5f * d * d : ad - 0.5f;
}

// Stage 1: per-(b, anchor-chunk) block. Computes CE for every anchor, pos flag via
// division-free IoU>=0.5 test; rare positives take the full argmax + smoothL1 path.
__global__ __launch_bounds__(256) void loss_main(
    const float* __restrict__ pred_cls,
    const float* __restrict__ pred_bbox,
    const float* __restrict__ pred_ldm,
    const float* __restrict__ anchors,
    const float* __restrict__ gt_boxes,
    const float* __restrict__ gt_ldm,
    float* __restrict__ partial)      // [4][BN][NBX]
{
    __shared__ float4 gtb[GN];
    __shared__ float  sg[GN];
    __shared__ float  gl[GN * 11];    // stride 11: gcd(11,32)=1 -> conflict-free gather
    __shared__ float  red[4][4];

    const int b   = blockIdx.y;
    const int tid = threadIdx.x;

    if (tid < GN) {
        float4 box = *(const float4*)(gt_boxes + (b * GN + tid) * 4);
        gtb[tid] = box;
        sg[tid]  = (box.z - box.x) * (box.w - box.y);
        const float* lp = gt_ldm + (b * GN + tid) * 10;
        #pragma unroll
        for (int j = 0; j < 10; ++j) gl[tid * 11 + j] = lp[j];
    }
    __syncthreads();

    const int a = blockIdx.x * 256 + tid;
    float ce = 0.f, np = 0.f, rl = 0.f, ll = 0.f;

    if (a < AN) {
        const float4 an4 = *(const float4*)(anchors + (size_t)a * 4);
        const float sa = (an4.z - an4.x) * (an4.w - an4.y);

        // Hot loop: boolean "IoU >= 0.5" only (2*inter >= union), no divide, no argmax.
        bool anypos = false;
        #pragma unroll
        for (int g = 0; g < GN; ++g) {
            float4 gb = gtb[g];
            float iw = fmaxf(fminf(an4.z, gb.z) - fmaxf(an4.x, gb.x), 0.f);
            float ih = fmaxf(fminf(an4.w, gb.w) - fmaxf(an4.y, gb.y), 0.f);
            float inter = iw * ih;
            float uni = sa + sg[g] - inter;
            anypos = anypos | (inter + inter >= uni);
        }

        // CE for every anchor (log_softmax over 2 logits).
        float2 pc = *(const float2*)(pred_cls + ((size_t)b * AN + a) * 2);
        float mx  = fmaxf(pc.x, pc.y);
        float lse = mx + logf(expf(pc.x - mx) + expf(pc.y - mx));
        ce = lse - (anypos ? pc.y : pc.x);

        // Cold path: only positive anchors (~32 per batch of 120000).
        if (anypos) {
            // Full argmax via cross-multiplication (denominators > 0; keeps first-max).
            float bi = -1.f, bu = 1.f; int bg = 0;
            #pragma unroll
            for (int g = 0; g < GN; ++g) {
                float4 gb = gtb[g];
                float iw = fmaxf(fminf(an4.z, gb.z) - fmaxf(an4.x, gb.x), 0.f);
                float ih = fmaxf(fminf(an4.w, gb.w) - fmaxf(an4.y, gb.y), 0.f);
                float inter = iw * ih;
                float uni = sa + sg[g] - inter;
                bool upd = inter * bu > bi * uni;
                bi = upd ? inter : bi;
                bu = upd ? uni   : bu;
                bg = upd ? g     : bg;
            }
            np = 1.f;
            float4 gb = gtb[bg];
            float aw = an4.z - an4.x, ah = an4.w - an4.y;
            float acx = an4.x + 0.5f * aw, acy = an4.y + 0.5f * ah;
            float gw = gb.z - gb.x, gh = gb.w - gb.y;
            float gcx = gb.x + 0.5f * gw, gcy = gb.y + 0.5f * gh;
            float t0 = (gcx - acx) / aw;
            float t1 = (gcy - acy) / ah;
            float t2 = logf(gw / aw);
            float t3 = logf(gh / ah);
            const float4 pb = *(const float4*)(pred_bbox + ((size_t)b * AN + a) * 4);
            rl = sl1(pb.x - t0) + sl1(pb.y - t1) + sl1(pb.z - t2) + sl1(pb.w - t3);
            const float* pl = pred_ldm + ((size_t)b * AN + a) * 10;
            float s = 0.f;
            #pragma unroll
            for (int j = 0; j < 10; ++j) s += sl1(pl[j] - gl[bg * 11 + j]);
            ll = s;
        }
    }

    // Block reduction: wave shuffle then cross-wave via LDS. No atomics anywhere.
    #pragma unroll
    for (int off = 32; off > 0; off >>= 1) {
        ce += __shfl_down(ce, off, 64);
        np += __shfl_down(np, off, 64);
        rl += __shfl_down(rl, off, 64);
        ll += __shfl_down(ll, off, 64);
    }
    const int lane = tid & 63, wid = tid >> 6;
    if (lane == 0) { red[0][wid] = ce; red[1][wid] = np; red[2][wid] = rl; red[3][wid] = ll; }
    __syncthreads();
    if (tid < 4) {
        float s = red[tid][0] + red[tid][1] + red[tid][2] + red[tid][3];
        partial[(size_t)tid * (BN * NBX) + (size_t)b * NBX + blockIdx.x] = s;
    }
}

// Stage 2: one block per (quantity q, batch b) reduces NBX partials.
__global__ __launch_bounds__(256) void reduce_partials(
    const float* __restrict__ partial, float* __restrict__ sums)
{
    const int qb = blockIdx.x;            // q*16 + b
    const float* p = partial + (size_t)qb * NBX;
    float s = 0.f;
    for (int t = threadIdx.x; t < NBX; t += 256) s += p[t];
    #pragma unroll
    for (int off = 32; off > 0; off >>= 1) s += __shfl_down(s, off, 64);
    __shared__ float red[4];
    if ((threadIdx.x & 63) == 0) red[threadIdx.x >> 6] = s;
    __syncthreads();
    if (threadIdx.x == 0) sums[qb] = red[0] + red[1] + red[2] + red[3];
}

// Stage 3: final scalar math.
__global__ void finalize(const float* __restrict__ sums, float* __restrict__ out)
{
    if (threadIdx.x == 0 && blockIdx.x == 0) {
        float cls = 0.f, reg = 0.f, ldm = 0.f;
        for (int b = 0; b < BN; ++b) {
            cls += sums[0 * BN + b] / (float)AN;
            float npv = sums[1 * BN + b];
            float denom = fmaxf(npv, 1.f);
            bool has = npv > 0.f;
            reg += has ? sums[2 * BN + b] / (denom * 4.f)  : 0.f;
            ldm += has ? sums[3 * BN + b] / (denom * 10.f) : 0.f;
        }
        cls /= (float)BN; reg /= (float)BN; ldm /= (float)BN;
        out[0] = cls + reg + ldm;
        out[1] = cls;
        out[2] = reg;
        out[3] = ldm;
    }
}

extern "C" void kernel_launch(void* const* d_in, const int* in_sizes, int n_in,
                              void* d_out, int out_size, void* d_ws, size_t ws_size,
                              hipStream_t stream) {
    const float* pred_cls  = (const float*)d_in[0];
    const float* pred_bbox = (const float*)d_in[1];
    const float* pred_ldm  = (const float*)d_in[2];
    const float* anchors   = (const float*)d_in[3];
    const float* gt_boxes  = (const float*)d_in[4];
    const float* gt_ldm    = (const float*)d_in[5];
    float* out = (float*)d_out;

    float* partial = (float*)d_ws;                 // 4*16*469 floats = 120064 B
    float* sums    = partial + 4 * BN * NBX;       // 64 floats

    dim3 grid1(NBX, BN);
    loss_main<<<grid1, 256, 0, stream>>>(pred_cls, pred_bbox, pred_ldm,
                                         anchors, gt_boxes, gt_ldm, partial);
    reduce_partials<<<4 * BN, 256, 0, stream>>>(partial, sums);
    finalize<<<1, 64, 0, stream>>>(sums, out);
}